// Round 11
// baseline (319.153 us; speedup 1.0000x reference)
//
#include <hip/hip_runtime.h>
#include <hip/hip_bf16.h>

#define N_NODES    100000
#define N_EDGES    1200000
#define HIDDEN     64
#define NUM_ATOM   100
#define SCAN_BLOCK 256

// ---------------------------------------------------------------------------
// rank[e] = deg[row[e]]++   (int atomics, L2-resident histogram; rank seq write)
__global__ void deg_rank_kernel(const int* __restrict__ row,
                                int* __restrict__ deg, int* __restrict__ rank) {
    int e = blockIdx.x * blockDim.x + threadIdx.x;
    if (e >= N_EDGES) return;
    rank[e] = atomicAdd(&deg[row[e]], 1);
}

// Block-level exclusive scan (Hillis-Steele) + per-block sums
__global__ void scan1_kernel(const int* __restrict__ deg, int* __restrict__ offs,
                             int* __restrict__ bsums) {
    __shared__ int tmp[SCAN_BLOCK];
    int i = blockIdx.x * SCAN_BLOCK + threadIdx.x;
    int v = (i < N_NODES) ? deg[i] : 0;
    tmp[threadIdx.x] = v;
    __syncthreads();
    for (int off = 1; off < SCAN_BLOCK; off <<= 1) {
        int t = (threadIdx.x >= off) ? tmp[threadIdx.x - off] : 0;
        __syncthreads();
        tmp[threadIdx.x] += t;
        __syncthreads();
    }
    if (i < N_NODES) offs[i] = tmp[threadIdx.x] - v;   // exclusive
    if (threadIdx.x == SCAN_BLOCK - 1) bsums[blockIdx.x] = tmp[threadIdx.x];
}

__global__ void scan2_kernel(int* __restrict__ bsums, int nb) {
    __shared__ int tmp[512];
    int v = (threadIdx.x < nb) ? bsums[threadIdx.x] : 0;
    tmp[threadIdx.x] = v;
    __syncthreads();
    for (int off = 1; off < 512; off <<= 1) {
        int t = (threadIdx.x >= off) ? tmp[threadIdx.x - off] : 0;
        __syncthreads();
        tmp[threadIdx.x] += t;
        __syncthreads();
    }
    if (threadIdx.x < nb) bsums[threadIdx.x] = tmp[threadIdx.x] - v;  // exclusive
}

__global__ void scan3_kernel(int* __restrict__ offs, const int* __restrict__ bsums) {
    int i = blockIdx.x * SCAN_BLOCK + threadIdx.x;
    if (i >= N_NODES) return;
    offs[i] += bsums[blockIdx.x];
}

// csr_col[offs[row[e]] + rank[e]] = col[e]   (no atomics)
__global__ void fill_kernel(const int* __restrict__ row, const int* __restrict__ col,
                            const int* __restrict__ offs, const int* __restrict__ rank,
                            int* __restrict__ csr_col) {
    int e = blockIdx.x * blockDim.x + threadIdx.x;
    if (e >= N_EDGES) return;
    csr_col[offs[row[e]] + rank[e]] = col[e];
}

// ---------------------------------------------------------------------------
// h0[n][f] = bf16(emb[z[n]][f]); thread handles 4 features (float4 -> 8B store)
__global__ void embed_kernel(const int* __restrict__ z,
                             const float* __restrict__ emb,
                             __hip_bfloat16* __restrict__ xout) {
    int t = blockIdx.x * blockDim.x + threadIdx.x;
    if (t >= N_NODES * 16) return;
    int n  = t >> 4;
    int f4 = (t & 15) << 2;
    float4 v = *reinterpret_cast<const float4*>(emb + z[n] * 64 + f4);
    __hip_bfloat16 o4[4];
    o4[0] = __float2bfloat16(v.x);
    o4[1] = __float2bfloat16(v.y);
    o4[2] = __float2bfloat16(v.z);
    o4[3] = __float2bfloat16(v.w);
    *reinterpret_cast<ushort4*>(xout + n * 64 + f4) =
        *reinterpret_cast<const ushort4*>(o4);
}

// ---------------------------------------------------------------------------
__device__ __forceinline__ float bf_lo(unsigned v) {
    return __uint_as_float(v << 16);
}
__device__ __forceinline__ float bf_hi(unsigned v) {
    return __uint_as_float(v & 0xffff0000u);
}

// Layers: TWO nodes per wave (half-wave each), packed bf16x2 gather (4 B/lane
// -> one VMEM instr fetches two 128 B rows). f32 accumulate; 8+4+scalar
// gather cascade (avg deg 12 -> one 8-iter + one 4-iter, no tail).
// Matvec runs full-wave per node (W via LDS). ReLU. LAST writes f32 to d_out.
template<bool LAST>
__global__ __launch_bounds__(256) void layer_kernel(
        const __hip_bfloat16* __restrict__ xin,
        __hip_bfloat16* __restrict__ xout_b,
        float* __restrict__ xout_f,
        const int* __restrict__ offs, const int* __restrict__ csr_col,
        const float* __restrict__ W, const float* __restrict__ b) {
    __shared__ float Ws[64][65];
    __shared__ float xs[4][2][64];   // [wave][half][feature]

    int t = threadIdx.x;
    for (int i = t; i < 4096; i += 256) Ws[i >> 6][i & 63] = W[i];
    __syncthreads();

    int lane = t & 63, w = t >> 6;
    int half = lane >> 5, m = lane & 31;
    float Wr[64];
    #pragma unroll
    for (int k = 0; k < 64; ++k) Wr[k] = Ws[lane][k];
    float bb = b[lane];

    const unsigned* __restrict__ xin32 = (const unsigned*)xin;  // [n][32] bf16x2
    int stride = gridDim.x * 4 * 2;                             // nodes per sweep

    for (int n0 = (blockIdx.x * 4 + w) * 2; n0 < N_NODES; n0 += stride) {
        int n = n0 + half;                   // this half's node (N_NODES even)
        int s = offs[n];
        int e = (n == N_NODES - 1) ? N_EDGES : offs[n + 1];

        unsigned rv = xin32[n * 32 + m];     // residual (feature pair)
        float accx = bf_lo(rv), accy = bf_hi(rv);
        float a0x=0.f,a0y=0.f,a1x=0.f,a1y=0.f,a2x=0.f,a2y=0.f,a3x=0.f,a3y=0.f;

        int k = s;
        for (; k + 7 < e; k += 8) {          // 8 in-flight loads
            int c0 = csr_col[k],     c1 = csr_col[k + 1];
            int c2 = csr_col[k + 2], c3 = csr_col[k + 3];
            int c4 = csr_col[k + 4], c5 = csr_col[k + 5];
            int c6 = csr_col[k + 6], c7 = csr_col[k + 7];
            unsigned v0 = xin32[c0 * 32 + m];
            unsigned v1 = xin32[c1 * 32 + m];
            unsigned v2 = xin32[c2 * 32 + m];
            unsigned v3 = xin32[c3 * 32 + m];
            unsigned v4 = xin32[c4 * 32 + m];
            unsigned v5 = xin32[c5 * 32 + m];
            unsigned v6 = xin32[c6 * 32 + m];
            unsigned v7 = xin32[c7 * 32 + m];
            a0x += bf_lo(v0); a0y += bf_hi(v0);
            a1x += bf_lo(v1); a1y += bf_hi(v1);
            a2x += bf_lo(v2); a2y += bf_hi(v2);
            a3x += bf_lo(v3); a3y += bf_hi(v3);
            a0x += bf_lo(v4); a0y += bf_hi(v4);
            a1x += bf_lo(v5); a1y += bf_hi(v5);
            a2x += bf_lo(v6); a2y += bf_hi(v6);
            a3x += bf_lo(v7); a3y += bf_hi(v7);
        }
        for (; k + 3 < e; k += 4) {          // 4 in-flight
            int c0 = csr_col[k],     c1 = csr_col[k + 1];
            int c2 = csr_col[k + 2], c3 = csr_col[k + 3];
            unsigned v0 = xin32[c0 * 32 + m];
            unsigned v1 = xin32[c1 * 32 + m];
            unsigned v2 = xin32[c2 * 32 + m];
            unsigned v3 = xin32[c3 * 32 + m];
            a0x += bf_lo(v0); a0y += bf_hi(v0);
            a1x += bf_lo(v1); a1y += bf_hi(v1);
            a2x += bf_lo(v2); a2y += bf_hi(v2);
            a3x += bf_lo(v3); a3y += bf_hi(v3);
        }
        for (; k < e; ++k) {
            unsigned v = xin32[csr_col[k] * 32 + m];
            accx += bf_lo(v); accy += bf_hi(v);
        }
        accx += (a0x + a1x) + (a2x + a3x);
        accy += (a0y + a1y) + (a2y + a3y);

        xs[w][half][2 * m]     = accx;       // wave-synchronous exchange
        xs[w][half][2 * m + 1] = accy;

        #pragma unroll
        for (int j = 0; j < 2; ++j) {        // matvec per node, full wave
            float o = bb;
            #pragma unroll
            for (int k4 = 0; k4 < 16; ++k4) {
                float4 xv = *reinterpret_cast<const float4*>(&xs[w][j][k4 * 4]);
                o = fmaf(xv.x, Wr[k4*4+0], o);
                o = fmaf(xv.y, Wr[k4*4+1], o);
                o = fmaf(xv.z, Wr[k4*4+2], o);
                o = fmaf(xv.w, Wr[k4*4+3], o);
            }
            o = fmaxf(o, 0.0f);
            int nn = n0 + j;
            if (LAST) xout_f[nn * 64 + lane] = o;
            else      xout_b[nn * 64 + lane] = __float2bfloat16(o);
        }
    }
}

// ---------------------------------------------------------------------------
extern "C" void kernel_launch(void* const* d_in, const int* in_sizes, int n_in,
                              void* d_out, int out_size, void* d_ws, size_t ws_size,
                              hipStream_t stream) {
    const int*   z          = (const int*)d_in[0];
    const int*   edge_index = (const int*)d_in[1];
    const float* emb        = (const float*)d_in[2];
    const float* W          = (const float*)d_in[3];
    const float* b          = (const float*)d_in[4];

    const int* row = edge_index;             // edge_index[0]
    const int* col = edge_index + N_EDGES;   // edge_index[1]

    float* x_out = (float*)d_out;            // [N][64] f32 (final only)

    // workspace layout (rank aliases xb_a: rank dead after fill, before embed)
    char* wsb = (char*)d_ws;
    __hip_bfloat16* xb_a = (__hip_bfloat16*)wsb;                // 12,800,000 B
    int*            rank = (int*)wsb;                           // 4,800,000 B alias
    __hip_bfloat16* xb_b = (__hip_bfloat16*)(wsb + 12800000);   // 12,800,000 B
    int*   csr_col = (int*)(wsb + 25600000);                    //  4,800,000 B
    int*   deg     = (int*)(wsb + 30400000);                    //    400,128 B
    int*   offs    = (int*)(wsb + 30800128);                    //    400,128 B
    int*   bsums   = (int*)(wsb + 31200256);                    //      2,048 B

    const int nb = (N_NODES + SCAN_BLOCK - 1) / SCAN_BLOCK;     // 391

    // ---- build CSR ----
    hipMemsetAsync(deg, 0, N_NODES * sizeof(int), stream);
    deg_rank_kernel<<<(N_EDGES + 255) / 256, 256, 0, stream>>>(row, deg, rank);
    scan1_kernel<<<nb, SCAN_BLOCK, 0, stream>>>(deg, offs, bsums);
    scan2_kernel<<<1, 512, 0, stream>>>(bsums, nb);
    scan3_kernel<<<nb, SCAN_BLOCK, 0, stream>>>(offs, bsums);
    fill_kernel<<<(N_EDGES + 255) / 256, 256, 0, stream>>>(row, col, offs, rank, csr_col);

    // ---- embed (after fill: xb_a aliases rank) ----
    embed_kernel<<<(N_NODES * 16 + 255) / 256, 256, 0, stream>>>(z, emb, xb_a);

    // ---- 3 layers: L1: xb_a->xb_b, L2: xb_b->xb_a, L3: xb_a->d_out ----
    layer_kernel<false><<<1280, 256, 0, stream>>>(xb_a, xb_b, (float*)nullptr,
                                                  offs, csr_col,
                                                  W + 0 * HIDDEN * HIDDEN, b + 0 * HIDDEN);
    layer_kernel<false><<<1280, 256, 0, stream>>>(xb_b, xb_a, (float*)nullptr,
                                                  offs, csr_col,
                                                  W + 1 * HIDDEN * HIDDEN, b + 1 * HIDDEN);
    layer_kernel<true><<<1280, 256, 0, stream>>>(xb_a, (__hip_bfloat16*)nullptr, x_out,
                                                 offs, csr_col,
                                                 W + 2 * HIDDEN * HIDDEN, b + 2 * HIDDEN);
}

// Round 12
// 248.409 us; speedup vs baseline: 1.2848x; 1.2848x over previous
//
#include <hip/hip_runtime.h>
#include <hip/hip_bf16.h>

#define N_NODES    100000
#define N_EDGES    1200000
#define HIDDEN     64
#define NUM_ATOM   100
#define SCAN_BLOCK 256
#define DEG_STRIDE 32   // one counter per 128 B line -> low atomic contention

// ---------------------------------------------------------------------------
// rank[e] = deg[row[e]*32]++  (padded histogram: ~12 atomics/line vs 192)
__global__ void deg_rank_kernel(const int* __restrict__ row,
                                int* __restrict__ deg, int* __restrict__ rank) {
    int e = blockIdx.x * blockDim.x + threadIdx.x;
    if (e >= N_EDGES) return;
    rank[e] = atomicAdd(&deg[row[e] * DEG_STRIDE], 1);
}

// Block-level exclusive scan (Hillis-Steele) + per-block sums; reads padded deg
__global__ void scan1_kernel(const int* __restrict__ deg, int* __restrict__ offs,
                             int* __restrict__ bsums) {
    __shared__ int tmp[SCAN_BLOCK];
    int i = blockIdx.x * SCAN_BLOCK + threadIdx.x;
    int v = (i < N_NODES) ? deg[i * DEG_STRIDE] : 0;
    tmp[threadIdx.x] = v;
    __syncthreads();
    for (int off = 1; off < SCAN_BLOCK; off <<= 1) {
        int t = (threadIdx.x >= off) ? tmp[threadIdx.x - off] : 0;
        __syncthreads();
        tmp[threadIdx.x] += t;
        __syncthreads();
    }
    if (i < N_NODES) offs[i] = tmp[threadIdx.x] - v;   // exclusive
    if (threadIdx.x == SCAN_BLOCK - 1) bsums[blockIdx.x] = tmp[threadIdx.x];
}

__global__ void scan2_kernel(int* __restrict__ bsums, int nb) {
    __shared__ int tmp[512];
    int v = (threadIdx.x < nb) ? bsums[threadIdx.x] : 0;
    tmp[threadIdx.x] = v;
    __syncthreads();
    for (int off = 1; off < 512; off <<= 1) {
        int t = (threadIdx.x >= off) ? tmp[threadIdx.x - off] : 0;
        __syncthreads();
        tmp[threadIdx.x] += t;
        __syncthreads();
    }
    if (threadIdx.x < nb) bsums[threadIdx.x] = tmp[threadIdx.x] - v;  // exclusive
}

__global__ void scan3_kernel(int* __restrict__ offs, const int* __restrict__ bsums) {
    int i = blockIdx.x * SCAN_BLOCK + threadIdx.x;
    if (i >= N_NODES) return;
    offs[i] += bsums[blockIdx.x];
}

// csr_col[offs[row[e]] + rank[e]] = col[e]   (no atomics)
__global__ void fill_kernel(const int* __restrict__ row, const int* __restrict__ col,
                            const int* __restrict__ offs, const int* __restrict__ rank,
                            int* __restrict__ csr_col) {
    int e = blockIdx.x * blockDim.x + threadIdx.x;
    if (e >= N_EDGES) return;
    csr_col[offs[row[e]] + rank[e]] = col[e];
}

// ---------------------------------------------------------------------------
// h0[n][f] = bf16(emb[z[n]][f]); thread handles 4 features (float4 -> 8B store)
__global__ void embed_kernel(const int* __restrict__ z,
                             const float* __restrict__ emb,
                             __hip_bfloat16* __restrict__ xout) {
    int t = blockIdx.x * blockDim.x + threadIdx.x;
    if (t >= N_NODES * 16) return;
    int n  = t >> 4;
    int f4 = (t & 15) << 2;
    float4 v = *reinterpret_cast<const float4*>(emb + z[n] * 64 + f4);
    __hip_bfloat16 o4[4];
    o4[0] = __float2bfloat16(v.x);
    o4[1] = __float2bfloat16(v.y);
    o4[2] = __float2bfloat16(v.z);
    o4[3] = __float2bfloat16(v.w);
    *reinterpret_cast<ushort4*>(xout + n * 64 + f4) =
        *reinterpret_cast<const ushort4*>(o4);
}

// ---------------------------------------------------------------------------
__device__ __forceinline__ float bf_lo(unsigned v) {
    return __uint_as_float(v << 16);
}
__device__ __forceinline__ float bf_hi(unsigned v) {
    return __uint_as_float(v & 0xffff0000u);
}

// Layers (round-9 proven config): TWO nodes per wave (half-wave each), packed
// bf16x2 gather (4 B/lane -> one VMEM instr fetches two 128 B rows). f32
// accumulate, 4 independent chains per half. Matvec full-wave per node.
// ReLU. LAST writes f32 to d_out.
template<bool LAST>
__global__ __launch_bounds__(256) void layer_kernel(
        const __hip_bfloat16* __restrict__ xin,
        __hip_bfloat16* __restrict__ xout_b,
        float* __restrict__ xout_f,
        const int* __restrict__ offs, const int* __restrict__ csr_col,
        const float* __restrict__ W, const float* __restrict__ b) {
    __shared__ float Ws[64][65];
    __shared__ float xs[4][2][64];   // [wave][half][feature]

    int t = threadIdx.x;
    for (int i = t; i < 4096; i += 256) Ws[i >> 6][i & 63] = W[i];
    __syncthreads();

    int lane = t & 63, w = t >> 6;
    int half = lane >> 5, m = lane & 31;
    float Wr[64];
    #pragma unroll
    for (int k = 0; k < 64; ++k) Wr[k] = Ws[lane][k];
    float bb = b[lane];

    const unsigned* __restrict__ xin32 = (const unsigned*)xin;  // [n][32] bf16x2
    int stride = gridDim.x * 4 * 2;                             // nodes per sweep

    for (int n0 = (blockIdx.x * 4 + w) * 2; n0 < N_NODES; n0 += stride) {
        int n = n0 + half;                   // this half's node (N_NODES even)
        int s = offs[n];
        int e = (n == N_NODES - 1) ? N_EDGES : offs[n + 1];

        unsigned rv = xin32[n * 32 + m];     // residual (feature pair)
        float accx = bf_lo(rv), accy = bf_hi(rv);
        float a0x=0.f,a0y=0.f,a1x=0.f,a1y=0.f,a2x=0.f,a2y=0.f,a3x=0.f,a3y=0.f;

        int k = s;
        for (; k + 3 < e; k += 4) {
            int c0 = csr_col[k],     c1 = csr_col[k + 1];
            int c2 = csr_col[k + 2], c3 = csr_col[k + 3];
            unsigned v0 = xin32[c0 * 32 + m];
            unsigned v1 = xin32[c1 * 32 + m];
            unsigned v2 = xin32[c2 * 32 + m];
            unsigned v3 = xin32[c3 * 32 + m];
            a0x += bf_lo(v0); a0y += bf_hi(v0);
            a1x += bf_lo(v1); a1y += bf_hi(v1);
            a2x += bf_lo(v2); a2y += bf_hi(v2);
            a3x += bf_lo(v3); a3y += bf_hi(v3);
        }
        for (; k < e; ++k) {
            unsigned v = xin32[csr_col[k] * 32 + m];
            accx += bf_lo(v); accy += bf_hi(v);
        }
        accx += (a0x + a1x) + (a2x + a3x);
        accy += (a0y + a1y) + (a2y + a3y);

        xs[w][half][2 * m]     = accx;       // wave-synchronous exchange
        xs[w][half][2 * m + 1] = accy;

        #pragma unroll
        for (int j = 0; j < 2; ++j) {        // matvec per node, full wave
            float o = bb;
            #pragma unroll
            for (int k4 = 0; k4 < 16; ++k4) {
                float4 xv = *reinterpret_cast<const float4*>(&xs[w][j][k4 * 4]);
                o = fmaf(xv.x, Wr[k4*4+0], o);
                o = fmaf(xv.y, Wr[k4*4+1], o);
                o = fmaf(xv.z, Wr[k4*4+2], o);
                o = fmaf(xv.w, Wr[k4*4+3], o);
            }
            o = fmaxf(o, 0.0f);
            int nn = n0 + j;
            if (LAST) xout_f[nn * 64 + lane] = o;
            else      xout_b[nn * 64 + lane] = __float2bfloat16(o);
        }
    }
}

// ---------------------------------------------------------------------------
extern "C" void kernel_launch(void* const* d_in, const int* in_sizes, int n_in,
                              void* d_out, int out_size, void* d_ws, size_t ws_size,
                              hipStream_t stream) {
    const int*   z          = (const int*)d_in[0];
    const int*   edge_index = (const int*)d_in[1];
    const float* emb        = (const float*)d_in[2];
    const float* W          = (const float*)d_in[3];
    const float* b          = (const float*)d_in[4];

    const int* row = edge_index;             // edge_index[0]
    const int* col = edge_index + N_EDGES;   // edge_index[1]

    float* x_out = (float*)d_out;            // [N][64] f32 (final only)

    // workspace layout with lifetime-based aliasing:
    //   rank    (4.8 MB)  aliases xb_a  — dead after fill, before embed writes
    //   deg_pad (12.8 MB) aliases xb_b  — dead after scan1, before L1 writes
    char* wsb = (char*)d_ws;
    __hip_bfloat16* xb_a = (__hip_bfloat16*)wsb;                // 12,800,000 B
    int*            rank = (int*)wsb;                           // alias of xb_a
    __hip_bfloat16* xb_b = (__hip_bfloat16*)(wsb + 12800000);   // 12,800,000 B
    int*            deg  = (int*)(wsb + 12800000);              // alias of xb_b (padded x32)
    int*   csr_col = (int*)(wsb + 25600000);                    //  4,800,000 B
    int*   offs    = (int*)(wsb + 30400000);                    //    400,128 B
    int*   bsums   = (int*)(wsb + 30800128);                    //      2,048 B

    const int nb = (N_NODES + SCAN_BLOCK - 1) / SCAN_BLOCK;     // 391

    // ---- build CSR ----
    hipMemsetAsync(deg, 0, (size_t)N_NODES * DEG_STRIDE * sizeof(int), stream);
    deg_rank_kernel<<<(N_EDGES + 255) / 256, 256, 0, stream>>>(row, deg, rank);
    scan1_kernel<<<nb, SCAN_BLOCK, 0, stream>>>(deg, offs, bsums);
    scan2_kernel<<<1, 512, 0, stream>>>(bsums, nb);
    scan3_kernel<<<nb, SCAN_BLOCK, 0, stream>>>(offs, bsums);
    fill_kernel<<<(N_EDGES + 255) / 256, 256, 0, stream>>>(row, col, offs, rank, csr_col);

    // ---- embed (after fill: xb_a aliases rank) ----
    embed_kernel<<<(N_NODES * 16 + 255) / 256, 256, 0, stream>>>(z, emb, xb_a);

    // ---- 3 layers: L1: xb_a->xb_b (overwrites dead deg_pad), L2: xb_b->xb_a,
    //      L3: xb_a->d_out ----
    layer_kernel<false><<<1280, 256, 0, stream>>>(xb_a, xb_b, (float*)nullptr,
                                                  offs, csr_col,
                                                  W + 0 * HIDDEN * HIDDEN, b + 0 * HIDDEN);
    layer_kernel<false><<<1280, 256, 0, stream>>>(xb_b, xb_a, (float*)nullptr,
                                                  offs, csr_col,
                                                  W + 1 * HIDDEN * HIDDEN, b + 1 * HIDDEN);
    layer_kernel<true><<<1280, 256, 0, stream>>>(xb_a, (__hip_bfloat16*)nullptr, x_out,
                                                 offs, csr_col,
                                                 W + 2 * HIDDEN * HIDDEN, b + 2 * HIDDEN);
}